// Round 1
// baseline (5339.554 us; speedup 1.0000x reference)
//
#include <hip/hip_runtime.h>
#include <cmath>

#define B_ 64
#define M_ 128
#define T_ 21
#define D_ 1024

__device__ __forceinline__ float sigm(float x) { return 1.0f / (1.0f + expf(-x)); }

// ---------------- build Xaug = [gv | x_t] per (b,t) ----------------
__global__ __launch_bounds__(256)
void k_build_xaug(const float* __restrict__ enc, const int* __restrict__ obj_seq,
                  const float* __restrict__ bos_w, float* __restrict__ Xaug) {
    int b = blockIdx.x, t = blockIdx.y;
    int tid = threadIdx.x;
    const float* gv = enc + (size_t)b * 129 * 1024;  // row 0 = global feature
    const float* xr;
    if (t == 0) xr = bos_w;
    else {
        int idx = obj_seq[b * 20 + (t - 1)];
        idx = min(max(idx, 0), 127);
        xr = enc + ((size_t)b * 129 + 1 + idx) * 1024;
    }
    float* out = Xaug + ((size_t)b * T_ + t) * 2048;
    float4 v0 = *(const float4*)(gv + tid * 4);
    *(float4*)(out + tid * 4) = v0;
    float4 v1 = *(const float4*)(xr + tid * 4);
    *(float4*)(out + 1024 + tid * 4) = v1;
}

// ---------------- tiled fp32 GEMM: C = A @ W^T + bias1 + bias2 ----------------
// A: (Mrows, K) row-major (or REMAP: att_feats view of encoder_out)
// W: (N, K) row-major, ldw row stride. Grid: (N/128, ceil(Mrows/128)), 256 thr.
template <bool REMAP>
__global__ __launch_bounds__(256)
void k_gemm_nt(const float* __restrict__ A, int lda, const float* __restrict__ W, int ldw,
               const float* __restrict__ bias1, const float* __restrict__ bias2,
               float* __restrict__ C, int ldc, int Mrows, int K) {
    __shared__ float As[16][128];
    __shared__ float Ws[16][128];
    const int tid = threadIdx.x;
    const int tx = tid & 15, ty = tid >> 4;
    const int m0 = blockIdx.y * 128, n0 = blockIdx.x * 128;

    float acc[8][8];
#pragma unroll
    for (int i = 0; i < 8; ++i)
#pragma unroll
        for (int j = 0; j < 8; ++j) acc[i][j] = 0.f;

    for (int k0 = 0; k0 < K; k0 += 16) {
#pragma unroll
        for (int l = 0; l < 2; ++l) {
            int f = tid * 2 + l;      // 0..511
            int r = f >> 2;           // 0..127
            int c4 = (f & 3) * 4;     // 0,4,8,12
            int g = m0 + r;
            float4 av = make_float4(0.f, 0.f, 0.f, 0.f);
            if (g < Mrows) {
                const float* rp;
                if (REMAP) rp = A + (((size_t)(g >> 7)) * 129 + 1 + (g & 127)) * 1024;
                else       rp = A + (size_t)g * lda;
                av = *(const float4*)(rp + k0 + c4);
            }
            As[c4 + 0][r] = av.x; As[c4 + 1][r] = av.y;
            As[c4 + 2][r] = av.z; As[c4 + 3][r] = av.w;
            float4 wv = *(const float4*)(W + (size_t)(n0 + r) * ldw + k0 + c4);
            Ws[c4 + 0][r] = wv.x; Ws[c4 + 1][r] = wv.y;
            Ws[c4 + 2][r] = wv.z; Ws[c4 + 3][r] = wv.w;
        }
        __syncthreads();
#pragma unroll
        for (int kk = 0; kk < 16; ++kk) {
            float4 a0 = *(const float4*)&As[kk][ty * 8];
            float4 a1 = *(const float4*)&As[kk][ty * 8 + 4];
            float4 w0 = *(const float4*)&Ws[kk][tx * 4];
            float4 w1 = *(const float4*)&Ws[kk][64 + tx * 4];
            float a[8] = {a0.x, a0.y, a0.z, a0.w, a1.x, a1.y, a1.z, a1.w};
            float w[8] = {w0.x, w0.y, w0.z, w0.w, w1.x, w1.y, w1.z, w1.w};
#pragma unroll
            for (int i = 0; i < 8; ++i)
#pragma unroll
                for (int j = 0; j < 8; ++j) acc[i][j] += a[i] * w[j];
        }
        __syncthreads();
    }
#pragma unroll
    for (int i = 0; i < 8; ++i) {
        int gm = m0 + ty * 8 + i;
        if (gm >= Mrows) continue;
#pragma unroll
        for (int half = 0; half < 2; ++half) {
            int gn = n0 + half * 64 + tx * 4;
            float4 v;
            float* pv = &v.x;
#pragma unroll
            for (int j = 0; j < 4; ++j) {
                float x = acc[i][half * 4 + j];
                if (bias1) x += bias1[gn + j];
                if (bias2) x += bias2[gn + j];
                pv[j] = x;
            }
            *(float4*)(C + (size_t)gm * ldc + gn) = v;
        }
    }
}

// ---------------- fused skinny gates GEMM + LSTM cell ----------------
// gates(64,4096) = sum_m hv[m] @ Wm[m]^T (+ addend row per b) (+ bias1+bias2), then LSTM.
// grid 256 blocks (4 d each), 256 threads.
template <int NMAT>
__global__ __launch_bounds__(256)
void k_lstm_cell(const float* __restrict__ hA, const float* __restrict__ WA, int ldwA,
                 const float* __restrict__ hB, const float* __restrict__ WB, int ldwB,
                 const float* __restrict__ hC, const float* __restrict__ WC, int ldwC,
                 const float* __restrict__ addend, int add_bstride,
                 const float* __restrict__ bias1, const float* __restrict__ bias2,
                 const float* __restrict__ c_prev, float* __restrict__ h_new,
                 float* __restrict__ c_new, float* __restrict__ out2, int out2_bstride) {
    __shared__ float sh[NMAT][64][68];  // [mat][k][b]
    __shared__ float sW[NMAT][16][68];  // [mat][n_idx][k]
    __shared__ float sg[4][64][5];      // [gate][b][jd]

    const int tid = threadIdx.x;
    const int wv = tid >> 6, lane = tid & 63;
    const int d0 = blockIdx.x * 4;
    const int n_idx = lane & 15;                      // 4 gates x 4 d
    const int b0 = (((wv << 2) | (lane >> 4)) << 2);  // 4 consecutive b
    const int gate = n_idx >> 2, jd = n_idx & 3;
    const int n = gate * 1024 + d0 + jd;

    const float* hv[3] = {hA, hB, hC};
    const float* Wm[3] = {WA, WB, WC};
    const int ldwm[3] = {ldwA, ldwB, ldwC};

    float4 accv = make_float4(0.f, 0.f, 0.f, 0.f);

    for (int k0 = 0; k0 < 1024; k0 += 64) {
#pragma unroll
        for (int m = 0; m < NMAT; ++m) {
            const float* hp = hv[m];
#pragma unroll
            for (int i = 0; i < 4; ++i) {
                int f = tid + i * 256;
                int r = f >> 4;            // b 0..63
                int c4 = (f & 15) * 4;     // k
                float4 v = *(const float4*)(hp + (size_t)r * 1024 + k0 + c4);
                sh[m][c4 + 0][r] = v.x; sh[m][c4 + 1][r] = v.y;
                sh[m][c4 + 2][r] = v.z; sh[m][c4 + 3][r] = v.w;
            }
            {
                int r = tid >> 4;          // n_idx 0..15
                int c4 = (tid & 15) * 4;
                int nn = (r >> 2) * 1024 + d0 + (r & 3);
                float4 v = *(const float4*)(Wm[m] + (size_t)nn * ldwm[m] + k0 + c4);
                *(float4*)&sW[m][r][c4] = v;
            }
        }
        __syncthreads();
#pragma unroll 4
        for (int kk4 = 0; kk4 < 16; ++kk4) {
#pragma unroll
            for (int m = 0; m < NMAT; ++m) {
                float4 w4 = *(const float4*)&sW[m][n_idx][kk4 * 4];
                float4 h0 = *(const float4*)&sh[m][kk4 * 4 + 0][b0];
                float4 h1 = *(const float4*)&sh[m][kk4 * 4 + 1][b0];
                float4 h2 = *(const float4*)&sh[m][kk4 * 4 + 2][b0];
                float4 h3 = *(const float4*)&sh[m][kk4 * 4 + 3][b0];
                accv.x += w4.x * h0.x + w4.y * h1.x + w4.z * h2.x + w4.w * h3.x;
                accv.y += w4.x * h0.y + w4.y * h1.y + w4.z * h2.y + w4.w * h3.y;
                accv.z += w4.x * h0.z + w4.y * h1.z + w4.z * h2.z + w4.w * h3.z;
                accv.w += w4.x * h0.w + w4.y * h1.w + w4.z * h2.w + w4.w * h3.w;
            }
        }
        __syncthreads();
    }

    float accs[4] = {accv.x, accv.y, accv.z, accv.w};
#pragma unroll
    for (int q = 0; q < 4; ++q) {
        int b = b0 + q;
        float g = accs[q];
        if (addend) g += addend[(size_t)b * add_bstride + n];
        if (bias1) g += bias1[n];
        if (bias2) g += bias2[n];
        sg[gate][b][jd] = g;
    }
    __syncthreads();
    {
        int b = tid & 63, j = tid >> 6;
        float gi = sg[0][b][j], gf = sg[1][b][j], gg = sg[2][b][j], go = sg[3][b][j];
        int d = d0 + j;
        float cp = c_prev[b * 1024 + d];
        float cn = sigm(gf) * cp + sigm(gi) * tanhf(gg);
        float hn = sigm(go) * tanhf(cn);
        c_new[b * 1024 + d] = cn;
        h_new[b * 1024 + d] = hn;
        if (out2) out2[(size_t)b * out2_bstride + d] = hn;
    }
}

// ---------------- ah = h1 @ Wah^T + bah ----------------
__global__ __launch_bounds__(256)
void k_ah(const float* __restrict__ h1, const float* __restrict__ Wah,
          const float* __restrict__ bah, float* __restrict__ ah) {
    __shared__ float sh[64][68];
    __shared__ float sW[4][68];
    int tid = threadIdx.x;
    int wv = tid >> 6, lane = tid & 63;
    int n0 = blockIdx.x * 4;
    float acc = 0.f;
    for (int k0 = 0; k0 < 1024; k0 += 64) {
#pragma unroll
        for (int i = 0; i < 4; ++i) {
            int f = tid + i * 256;
            int r = f >> 4, c4 = (f & 15) * 4;
            float4 v = *(const float4*)(h1 + (size_t)r * 1024 + k0 + c4);
            *(float4*)&sh[r][c4] = v;
        }
        sW[tid >> 6][tid & 63] = Wah[(size_t)(n0 + (tid >> 6)) * 1024 + k0 + (tid & 63)];
        __syncthreads();
#pragma unroll
        for (int kk4 = 0; kk4 < 16; ++kk4) {
            float4 w4 = *(const float4*)&sW[wv][kk4 * 4];
            float4 h4 = *(const float4*)&sh[lane][kk4 * 4];
            acc += w4.x * h4.x + w4.y * h4.y + w4.z * h4.z + w4.w * h4.w;
        }
        __syncthreads();
    }
    int n = n0 + wv;
    ah[lane * 1024 + n] = acc + bah[n];
}

// ---------------- score[b,m] = wa . tanh(p_att[b,m,:] + ah[b,:]) + ba ----------------
__global__ __launch_bounds__(256)
void k_score(const float* __restrict__ p_att, const float* __restrict__ ah,
             const float* __restrict__ wa, const float* __restrict__ ba,
             const int* __restrict__ att_mask, float* __restrict__ score) {
    int mc = blockIdx.x, b = blockIdx.y;
    __shared__ float sah[1024], swa[1024];
    __shared__ float red[4];
    int tid = threadIdx.x;
    {
        float4 v = *(const float4*)(ah + (size_t)b * 1024 + tid * 4);
        *(float4*)&sah[tid * 4] = v;
        float4 w = *(const float4*)(wa + tid * 4);
        *(float4*)&swa[tid * 4] = w;
    }
    __syncthreads();
    float bav = ba[0];
    float4 a4 = *(const float4*)&sah[tid * 4];
    float4 w4 = *(const float4*)&swa[tid * 4];
    for (int mi = 0; mi < 16; ++mi) {
        int m = mc * 16 + mi;
        const float* pr = p_att + ((size_t)b * 128 + m) * 1024;
        float4 p4 = *(const float4*)(pr + tid * 4);
        float part = tanhf(p4.x + a4.x) * w4.x + tanhf(p4.y + a4.y) * w4.y +
                     tanhf(p4.z + a4.z) * w4.z + tanhf(p4.w + a4.w) * w4.w;
#pragma unroll
        for (int off = 32; off; off >>= 1) part += __shfl_down(part, off, 64);
        if ((tid & 63) == 0) red[tid >> 6] = part;
        __syncthreads();
        if (tid == 0) {
            float s = red[0] + red[1] + red[2] + red[3] + bav;
            if (att_mask[b * 129 + 1 + m] == 0) s = -1e9f;
            score[b * 128 + m] = s;
        }
        __syncthreads();
    }
}

// ---------------- softmax(score) then att[b,d] = sum_m alpha[m]*att_feats[b,m,d] ----------------
__global__ __launch_bounds__(256)
void k_attsum(const float* __restrict__ score, const float* __restrict__ enc,
              float* __restrict__ att) {
    int dc = blockIdx.x, b = blockIdx.y;
    __shared__ float salpha[128];
    __shared__ float sred[8];
    int tid = threadIdx.x;
    float sv = (tid < 128) ? score[b * 128 + tid] : -INFINITY;
    float mx = sv;
#pragma unroll
    for (int off = 32; off; off >>= 1) mx = fmaxf(mx, __shfl_down(mx, off, 64));
    if ((tid & 63) == 0) sred[tid >> 6] = mx;
    __syncthreads();
    float gmx = fmaxf(fmaxf(sred[0], sred[1]), fmaxf(sred[2], sred[3]));
    float ev = (tid < 128) ? expf(sv - gmx) : 0.f;
    float s = ev;
#pragma unroll
    for (int off = 32; off; off >>= 1) s += __shfl_down(s, off, 64);
    if ((tid & 63) == 0) sred[4 + (tid >> 6)] = s;
    __syncthreads();
    float gsum = sred[4] + sred[5] + sred[6] + sred[7];
    if (tid < 128) salpha[tid] = ev / gsum;
    __syncthreads();
    int d = dc * 256 + tid;
    float acc = 0.f;
    const float* base = enc + ((size_t)b * 129 + 1) * 1024 + d;
#pragma unroll 8
    for (int m = 0; m < 128; ++m) acc += salpha[m] * base[(size_t)m * 1024];
    att[b * 1024 + d] = acc;
}

// ---------------- nce_logit[b,l,j] = ofe[b,l,:] . afe[b,j,:] ----------------
__global__ __launch_bounds__(256)
void k_nce(const float* __restrict__ OFE, const float* __restrict__ AFE,
           const float* __restrict__ eos_w, float* __restrict__ nce) {
    int l = blockIdx.x, b = blockIdx.y;
    __shared__ float sofe[1024];
    int tid = threadIdx.x;
    {
        float4 v = *(const float4*)(OFE + ((size_t)b * 21 + l) * 1024 + tid * 4);
        *(float4*)&sofe[tid * 4] = v;
    }
    __syncthreads();
    int w = tid >> 6, lane = tid & 63;
    float* outp = nce + ((size_t)b * 21 + l) * 129;
    for (int j = w; j < 129; j += 4) {
        const float* ar = (j == 0) ? eos_w : AFE + ((size_t)b * 128 + (j - 1)) * 1024;
        float part = 0.f;
#pragma unroll
        for (int c = 0; c < 4; ++c) {
            float4 a4 = *(const float4*)(ar + c * 256 + lane * 4);
            float4 o4 = *(const float4*)&sofe[c * 256 + lane * 4];
            part += a4.x * o4.x + a4.y * o4.y + a4.z * o4.z + a4.w * o4.w;
        }
#pragma unroll
        for (int off = 32; off; off >>= 1) part += __shfl_down(part, off, 64);
        if (lane == 0) outp[j] = part;
    }
}

extern "C" void kernel_launch(void* const* d_in, const int* in_sizes, int n_in,
                              void* d_out, int out_size, void* d_ws, size_t ws_size,
                              hipStream_t stream) {
    const float* enc   = (const float*)d_in[0];
    const int*   obj   = (const int*)d_in[1];
    const int*   amask = (const int*)d_in[2];
    const float* bos_w = (const float*)d_in[3];
    const float* eos_w = (const float*)d_in[4];
    const float* Wp    = (const float*)d_in[5];
    const float* bp    = (const float*)d_in[6];
    const float* Wih1  = (const float*)d_in[7];
    const float* Whh1  = (const float*)d_in[8];
    const float* bih1  = (const float*)d_in[9];
    const float* bhh1  = (const float*)d_in[10];
    const float* Wih2  = (const float*)d_in[11];
    const float* Whh2  = (const float*)d_in[12];
    const float* bih2  = (const float*)d_in[13];
    const float* bhh2  = (const float*)d_in[14];
    const float* Wah   = (const float*)d_in[15];
    const float* bah   = (const float*)d_in[16];
    const float* wa    = (const float*)d_in[17];
    const float* ba    = (const float*)d_in[18];
    const float* Wae   = (const float*)d_in[19];
    const float* bae   = (const float*)d_in[20];
    const float* Woe   = (const float*)d_in[21];
    const float* boe   = (const float*)d_in[22];

    float* outputs = (float*)d_out;                    // (64,21,1024)
    float* nce     = outputs + (size_t)64 * 21 * 1024; // (64,21,129)

    float* w = (float*)d_ws;
    float* Xaug = w; w += (size_t)1344 * 2048;
    float* Xc   = w; w += (size_t)1344 * 4096;
    float* Patt = w; w += (size_t)8192 * 1024;
    float* AFE  = w; w += (size_t)8192 * 1024;
    float* OFE  = w; w += (size_t)1344 * 1024;
    float* H1   = w; w += 2 * 65536;
    float* C1v  = w; w += 2 * 65536;
    float* H2   = w; w += 2 * 65536;
    float* C2v  = w; w += 2 * 65536;
    float* AH   = w; w += 65536;
    float* ATT  = w; w += 65536;
    float* SC   = w; w += 64 * 128;

    hipMemsetAsync(H1,  0, 65536 * 4, stream);
    hipMemsetAsync(C1v, 0, 65536 * 4, stream);
    hipMemsetAsync(H2,  0, 65536 * 4, stream);
    hipMemsetAsync(C2v, 0, 65536 * 4, stream);

    dim3 blk(256);
    k_build_xaug<<<dim3(64, 21), blk, 0, stream>>>(enc, obj, bos_w, Xaug);
    // p_att = att_feats @ Wp^T + bp
    k_gemm_nt<true ><<<dim3(8, 64), blk, 0, stream>>>(enc, 0, Wp, 1024, bp, nullptr, Patt, 1024, 8192, 1024);
    // Xc = [gv|x] @ Wih1[:,1024:3072]^T + bih1 + bhh1  (time-independent part of gates1)
    k_gemm_nt<false><<<dim3(32, 11), blk, 0, stream>>>(Xaug, 2048, Wih1 + 1024, 3072, bih1, bhh1, Xc, 4096, 1344, 2048);
    // afe body = att_feats @ Wae^T + bae
    k_gemm_nt<true ><<<dim3(8, 64), blk, 0, stream>>>(enc, 0, Wae, 1024, bae, nullptr, AFE, 1024, 8192, 1024);

    for (int t = 0; t < 21; ++t) {
        int p = t & 1, q = p ^ 1;
        // cell1: gates = Xc[t] + h2@Wih1[:,0:1024]^T + h1@Whh1^T
        k_lstm_cell<2><<<256, blk, 0, stream>>>(
            H2 + p * 65536, Wih1, 3072,
            H1 + p * 65536, Whh1, 1024,
            nullptr, nullptr, 0,
            Xc + (size_t)t * 4096, 21 * 4096,
            nullptr, nullptr,
            C1v + p * 65536, H1 + q * 65536, C1v + q * 65536,
            nullptr, 0);
        k_ah<<<256, blk, 0, stream>>>(H1 + q * 65536, Wah, bah, AH);
        k_score<<<dim3(8, 64), blk, 0, stream>>>(Patt, AH, wa, ba, amask, SC);
        k_attsum<<<dim3(4, 64), blk, 0, stream>>>(SC, enc, ATT);
        // cell2: gates = att@Wih2[:,0:1024]^T + h1@Wih2[:,1024:2048]^T + h2@Whh2^T + bih2 + bhh2
        k_lstm_cell<3><<<256, blk, 0, stream>>>(
            ATT, Wih2, 2048,
            H1 + q * 65536, Wih2 + 1024, 2048,
            H2 + p * 65536, Whh2, 1024,
            nullptr, 0,
            bih2, bhh2,
            C2v + p * 65536, H2 + q * 65536, C2v + q * 65536,
            outputs + (size_t)t * 1024, 21 * 1024);
    }
    // ofe = outputs @ Woe^T + boe
    k_gemm_nt<false><<<dim3(8, 11), blk, 0, stream>>>(outputs, 1024, Woe, 1024, boe, nullptr, OFE, 1024, 1344, 1024);
    k_nce<<<dim3(21, 64), blk, 0, stream>>>(OFE, AFE, eos_w, nce);
}

// Round 5
// 1810.671 us; speedup vs baseline: 2.9489x; 2.9489x over previous
//
#include <hip/hip_runtime.h>
#include <cmath>

typedef unsigned short u16;
typedef __attribute__((ext_vector_type(8))) short short8;
typedef __attribute__((ext_vector_type(4))) float floatx4;
typedef __attribute__((address_space(3))) unsigned int lds_u32;
typedef const __attribute__((address_space(1))) unsigned int glob_u32;

__device__ __forceinline__ u16 f2bf(float f) {
    unsigned u = __float_as_uint(f);
    unsigned r = u + 0x7fffu + ((u >> 16) & 1u);
    return (u16)(r >> 16);
}
__device__ __forceinline__ float bf2f(u16 h) { return __uint_as_float(((unsigned)h) << 16); }
__device__ __forceinline__ void split2(float x, u16& hi, u16& lo) {
    hi = f2bf(x);
    lo = f2bf(x - bf2f(hi));
}
__device__ __forceinline__ float sigm(float x) {
    x = fminf(fmaxf(x, -30.f), 30.f);
    return 1.0f / (1.0f + __expf(-x));
}
__device__ __forceinline__ float ftanh(float x) {
    x = fminf(fmaxf(x, -15.f), 15.f);
    float e = __expf(2.f * x);
    return (e - 1.f) / (e + 1.f);
}
__device__ __forceinline__ void gload16(const void* g, void* l) {
    __builtin_amdgcn_global_load_lds((glob_u32*)g, (lds_u32*)l, 16, 0, 0);
}

// ---------------- f32 -> bf16 (single) ----------------
__global__ __launch_bounds__(256) void k_cvt(const float* __restrict__ s, u16* __restrict__ d, int n4) {
    int i = blockIdx.x * 256 + threadIdx.x;
    int stride = gridDim.x * 256;
    for (; i < n4; i += stride) {
        float4 v = ((const float4*)s)[i];
        ushort4 o;
        o.x = f2bf(v.x); o.y = f2bf(v.y); o.z = f2bf(v.z); o.w = f2bf(v.w);
        ((ushort4*)d)[i] = o;
    }
}

// ---------------- f32 -> (hi, lo) bf16 planes ----------------
__global__ __launch_bounds__(256) void k_splitp(const float* __restrict__ s, u16* __restrict__ hi,
                                                u16* __restrict__ lo, int n4) {
    int i = blockIdx.x * 256 + threadIdx.x;
    int stride = gridDim.x * 256;
    for (; i < n4; i += stride) {
        float4 v = ((const float4*)s)[i];
        ushort4 h, l;
        split2(v.x, h.x, l.x); split2(v.y, h.y, l.y);
        split2(v.z, h.z, l.z); split2(v.w, h.w, l.w);
        ((ushort4*)hi)[i] = h;
        ((ushort4*)lo)[i] = l;
    }
}

// ---------------- weight concat builders (hi/lo planes) ----------------
// W1cat (4096 x 2048): [Wih1[:, :1024] | Whh1]
__global__ __launch_bounds__(256) void k_build_w1cat(const float* __restrict__ Wih1, const float* __restrict__ Whh1,
                                                     u16* __restrict__ dh, u16* __restrict__ dl) {
    int row = blockIdx.x;
    int c = threadIdx.x * 8;
    const float* src = (c < 1024) ? (Wih1 + (size_t)row * 3072 + c) : (Whh1 + (size_t)row * 1024 + (c - 1024));
    short8 h, l;
#pragma unroll
    for (int j = 0; j < 8; ++j) { u16 hh, ll; split2(src[j], hh, ll); h[j] = (short)hh; l[j] = (short)ll; }
    *(short8*)(dh + (size_t)row * 2048 + c) = h;
    *(short8*)(dl + (size_t)row * 2048 + c) = l;
}

// Wcat2 (4096 x 3072): [Wih2 | Whh2]   (384 threads)
__global__ __launch_bounds__(384) void k_build_wcat2(const float* __restrict__ Wih2, const float* __restrict__ Whh2,
                                                     u16* __restrict__ dh, u16* __restrict__ dl) {
    int row = blockIdx.x;
    int c = threadIdx.x * 8;
    const float* src = (c < 2048) ? (Wih2 + (size_t)row * 2048 + c) : (Whh2 + (size_t)row * 1024 + (c - 2048));
    short8 h, l;
#pragma unroll
    for (int j = 0; j < 8; ++j) { u16 hh, ll; split2(src[j], hh, ll); h[j] = (short)hh; l[j] = (short)ll; }
    *(short8*)(dh + (size_t)row * 3072 + c) = h;
    *(short8*)(dl + (size_t)row * 3072 + c) = l;
}

// Wx1 (4096 x 2048) = Wih1[:, 1024:3072]
__global__ __launch_bounds__(256) void k_build_wx1(const float* __restrict__ Wih1, u16* __restrict__ dh,
                                                   u16* __restrict__ dl) {
    int row = blockIdx.x;
    int c = threadIdx.x * 8;
    const float* src = Wih1 + (size_t)row * 3072 + 1024 + c;
    short8 h, l;
#pragma unroll
    for (int j = 0; j < 8; ++j) { u16 hh, ll; split2(src[j], hh, ll); h[j] = (short)hh; l[j] = (short)ll; }
    *(short8*)(dh + (size_t)row * 2048 + c) = h;
    *(short8*)(dl + (size_t)row * 2048 + c) = l;
}

// Xaug (1344 x 2048): [gv | x_t] hi/lo
__global__ __launch_bounds__(256) void k_build_xaug(const float* __restrict__ enc, const int* __restrict__ obj,
                                                    const float* __restrict__ bos_w, u16* __restrict__ dh,
                                                    u16* __restrict__ dl) {
    int b = blockIdx.x, t = blockIdx.y, tid = threadIdx.x;
    const float* gv = enc + (size_t)b * 129 * 1024;
    const float* xr;
    if (t == 0) xr = bos_w;
    else {
        int idx = obj[b * 20 + (t - 1)];
        idx = min(max(idx, 0), 127);
        xr = enc + ((size_t)b * 129 + 1 + idx) * 1024;
    }
    size_t rowoff = ((size_t)b * 21 + t) * 2048;
    float4 v0 = *(const float4*)(gv + tid * 4);
    float4 v1 = *(const float4*)(xr + tid * 4);
    ushort4 h0, l0, h1, l1;
    split2(v0.x, h0.x, l0.x); split2(v0.y, h0.y, l0.y); split2(v0.z, h0.z, l0.z); split2(v0.w, h0.w, l0.w);
    split2(v1.x, h1.x, l1.x); split2(v1.y, h1.y, l1.y); split2(v1.z, h1.z, l1.z); split2(v1.w, h1.w, l1.w);
    *(ushort4*)(dh + rowoff + tid * 4) = h0;
    *(ushort4*)(dl + rowoff + tid * 4) = l0;
    *(ushort4*)(dh + rowoff + 1024 + tid * 4) = h1;
    *(ushort4*)(dl + rowoff + 1024 + tid * 4) = l1;
}

// ---------------- MFMA GEMM: C = A @ W^T + b1 + b2, split-precision passes ----------------
template <int APASS, int BPASS, int AREMAP, bool BF16OUT>
__global__ __launch_bounds__(256)
void k_gemm3(const u16* __restrict__ Ah, const u16* __restrict__ Al, int lda,
             const u16* __restrict__ Wh, const u16* __restrict__ Wl, int ldw,
             const float* __restrict__ b1, const float* __restrict__ b2,
             void* __restrict__ Cout, int ldc, int Mrows, int K) {
    constexpr int NP = APASS + BPASS;
    __shared__ char lds[2][NP][8192];
    const int tid = threadIdx.x;
    const int lane = tid & 63;
    const int lr = lane & 15, lk = lane >> 4;
    const int m0 = blockIdx.y * 128, n0 = blockIdx.x * 128;
    const int wid = tid >> 6;
    const int wr = wid >> 1, wc = wid & 1;
    const int wbyte = (tid & 192) * 16;

    floatx4 acc[4][4] = {};
    const int nt = K >> 5;

    auto stage = [&](int bb, int kt) {
        int k0 = kt * 32;
#pragma unroll
        for (int i = 0; i < 2; ++i) {
            int p = i * 256 + tid;
            int s = p ^ ((p >> 2) & 3);
            int row = s >> 2, kc = s & 3;
            size_t aoff;
            int gm = m0 + row;
            if (AREMAP == 1) aoff = (((size_t)(gm >> 7)) * 129 + 1 + (gm & 127)) * 1024 + k0 + kc * 8;
            else {
                int cm = gm < Mrows ? gm : Mrows - 1;
                aoff = (size_t)cm * lda + k0 + kc * 8;
            }
            gload16(Ah + aoff, &lds[bb][0][i * 4096 + wbyte]);
            if constexpr (APASS == 2) gload16(Al + aoff, &lds[bb][1][i * 4096 + wbyte]);
            size_t woff = (size_t)(n0 + row) * ldw + k0 + kc * 8;
            gload16(Wh + woff, &lds[bb][APASS][i * 4096 + wbyte]);
            if constexpr (BPASS == 2) gload16(Wl + woff, &lds[bb][APASS + 1][i * 4096 + wbyte]);
        }
    };

    stage(0, 0);
    __syncthreads();
    for (int t = 0; t < nt; ++t) {
        int bb = t & 1;
        if (t + 1 < nt) stage(bb ^ 1, t + 1);
        short8 ah_[4], al_[4], bh_[4], bl_[4];
#pragma unroll
        for (int mi = 0; mi < 4; ++mi) {
            int row = wr * 64 + mi * 16 + lr;
            int slot = (row * 4 + (lk ^ (row & 3))) * 16;
            ah_[mi] = *(const short8*)&lds[bb][0][slot];
            if constexpr (APASS == 2) al_[mi] = *(const short8*)&lds[bb][1][slot];
        }
#pragma unroll
        for (int ni = 0; ni < 4; ++ni) {
            int row = wc * 64 + ni * 16 + lr;
            int slot = (row * 4 + (lk ^ (row & 3))) * 16;
            bh_[ni] = *(const short8*)&lds[bb][APASS][slot];
            if constexpr (BPASS == 2) bl_[ni] = *(const short8*)&lds[bb][APASS + 1][slot];
        }
#pragma unroll
        for (int mi = 0; mi < 4; ++mi)
#pragma unroll
            for (int ni = 0; ni < 4; ++ni) {
                acc[mi][ni] = __builtin_amdgcn_mfma_f32_16x16x32_bf16(ah_[mi], bh_[ni], acc[mi][ni], 0, 0, 0);
                if constexpr (BPASS == 2)
                    acc[mi][ni] = __builtin_amdgcn_mfma_f32_16x16x32_bf16(ah_[mi], bl_[ni], acc[mi][ni], 0, 0, 0);
                if constexpr (APASS == 2)
                    acc[mi][ni] = __builtin_amdgcn_mfma_f32_16x16x32_bf16(al_[mi], bh_[ni], acc[mi][ni], 0, 0, 0);
            }
        __syncthreads();
    }
#pragma unroll
    for (int mi = 0; mi < 4; ++mi) {
#pragma unroll
        for (int r = 0; r < 4; ++r) {
            int gm = m0 + wr * 64 + mi * 16 + lk * 4 + r;
            if (AREMAP == 0 && gm >= Mrows) continue;
#pragma unroll
            for (int ni = 0; ni < 4; ++ni) {
                int gn = n0 + wc * 64 + ni * 16 + lr;
                float v = acc[mi][ni][r];
                if (b1) v += b1[gn];
                if (b2) v += b2[gn];
                if (BF16OUT) ((u16*)Cout)[(size_t)gm * ldc + gn] = f2bf(v);
                else ((float*)Cout)[(size_t)gm * ldc + gn] = v;
            }
        }
    }
}

// ---------------- skinny split GEMM: P[kp] = X(64xK)[:,koff:+Klen] @ W^T slice, 3-pass ----------------
__global__ __launch_bounds__(256)
void k_gp3(const u16* __restrict__ Xh, const u16* __restrict__ Xl, int ldx,
           const u16* __restrict__ Wh, const u16* __restrict__ Wl, int ldw,
           int Klen, float* __restrict__ P, int Ntot) {
    __shared__ char lds[2][4][4096];
    const int tid = threadIdx.x, wid = tid >> 6, lane = tid & 63;
    const int lr = lane & 15, lk = lane >> 4;
    const int n0 = blockIdx.x * 64;
    const int koff = blockIdx.y * Klen;
    floatx4 acc[4] = {};
    const int nt = Klen >> 5;
    const int wbyte = (tid & 192) * 16;
    const int srow = tid >> 2, skc = (tid & 3) ^ (srow & 3);
    const size_t xoff = (size_t)srow * ldx + skc * 8;
    const size_t woff = (size_t)(n0 + srow) * ldw + skc * 8;

    auto stage = [&](int bb, int kt) {
        int k0 = koff + kt * 32;
        gload16(Xh + xoff + k0, &lds[bb][0][wbyte]);
        gload16(Xl + xoff + k0, &lds[bb][1][wbyte]);
        gload16(Wh + woff + k0, &lds[bb][2][wbyte]);
        gload16(Wl + woff + k0, &lds[bb][3][wbyte]);
    };

    stage(0, 0);
    __syncthreads();
    for (int t = 0; t < nt; ++t) {
        int bb = t & 1;
        if (t + 1 < nt) stage(bb ^ 1, t + 1);
        int arow = wid * 16 + lr;
        int aslot = (arow * 4 + (lk ^ (arow & 3))) * 16;
        short8 xh = *(const short8*)&lds[bb][0][aslot];
        short8 xl = *(const short8*)&lds[bb][1][aslot];
#pragma unroll
        for (int ni = 0; ni < 4; ++ni) {
            int brow = ni * 16 + lr;
            int bslot = (brow * 4 + (lk ^ (brow & 3))) * 16;
            short8 wh = *(const short8*)&lds[bb][2][bslot];
            short8 wl = *(const short8*)&lds[bb][3][bslot];
            acc[ni] = __builtin_amdgcn_mfma_f32_16x16x32_bf16(xh, wh, acc[ni], 0, 0, 0);
            acc[ni] = __builtin_amdgcn_mfma_f32_16x16x32_bf16(xh, wl, acc[ni], 0, 0, 0);
            acc[ni] = __builtin_amdgcn_mfma_f32_16x16x32_bf16(xl, wh, acc[ni], 0, 0, 0);
        }
        __syncthreads();
    }
    float* Pb = P + (size_t)blockIdx.y * 64 * Ntot;
#pragma unroll
    for (int ni = 0; ni < 4; ++ni)
#pragma unroll
        for (int r = 0; r < 4; ++r) {
            int b = wid * 16 + lk * 4 + r;
            Pb[(size_t)b * Ntot + n0 + ni * 16 + lr] = acc[ni][r];
        }
}

// ---------------- reduce partials + LSTM cell, split h outputs ----------------
__global__ __launch_bounds__(256)
void k_finish(const float* __restrict__ P, int Ntot, const float* __restrict__ xcf,
              const float* __restrict__ b1, const float* __restrict__ b2,
              float* __restrict__ cst,
              u16* __restrict__ w1h, u16* __restrict__ w1l, int w1s,
              u16* __restrict__ w2h, u16* __restrict__ w2l, int w2s,
              float* __restrict__ outf, u16* __restrict__ oh) {
    int idx = blockIdx.x * 256 + threadIdx.x;  // b*1024 + d
    int b = idx >> 10, d = idx & 1023;
    float g[4];
#pragma unroll
    for (int q = 0; q < 4; ++q) {
        int n = q * 1024 + d;
        float s = 0.f;
#pragma unroll
        for (int p = 0; p < 4; ++p) s += P[((size_t)p * 64 + b) * Ntot + n];
        if (xcf) s += xcf[(size_t)b * 21 * 4096 + n];
        if (b1) s += b1[n];
        if (b2) s += b2[n];
        g[q] = s;
    }
    float cp = cst[idx];
    float cn = sigm(g[1]) * cp + sigm(g[0]) * ftanh(g[2]);
    float hn = sigm(g[3]) * ftanh(cn);
    cst[idx] = cn;
    u16 hh, hl;
    split2(hn, hh, hl);
    w1h[b * w1s + d] = hh; w1l[b * w1s + d] = hl;
    w2h[b * w2s + d] = hh; w2l[b * w2s + d] = hl;
    if (outf) outf[(size_t)b * 21 * 1024 + d] = hn;
    if (oh) oh[(size_t)b * 21 * 1024 + d] = hh;
}

// ---------------- score: wa . tanh(p_att + ah) + ba, mask (f32 p_att; ah from 2 partials) ----------------
__global__ __launch_bounds__(256)
void k_score(const float* __restrict__ PAH, const float* __restrict__ bah,
             const float* __restrict__ wa, const float* __restrict__ ba,
             const float* __restrict__ Patt, const int* __restrict__ amask, float* __restrict__ SC) {
    int mc = blockIdx.x, b = blockIdx.y, tid = threadIdx.x;
    __shared__ float sah[1024], swa[1024];
    {
        int d = tid * 4;
        *(float4*)&swa[d] = *(const float4*)(wa + d);
        float4 s;
        float* sp = &s.x;
#pragma unroll
        for (int j = 0; j < 4; ++j) {
            float acc = bah[d + j];
            acc += PAH[(size_t)b * 1024 + d + j];
            acc += PAH[((size_t)64 + b) * 1024 + d + j];
            sp[j] = acc;
        }
        *(float4*)&sah[d] = s;
    }
    __syncthreads();
    int wv = tid >> 6, lane = tid & 63;
    float bav = ba[0];
    for (int j = 0; j < 8; ++j) {
        int m = mc * 32 + wv * 8 + j;
        const float* pr = Patt + ((size_t)(b * 128 + m)) * 1024;
        float part = 0.f;
#pragma unroll
        for (int c = 0; c < 4; ++c) {
            int d = c * 256 + lane * 4;
            float4 p4 = *(const float4*)(pr + d);
            float4 a4 = *(const float4*)&sah[d];
            float4 w4 = *(const float4*)&swa[d];
            part += ftanh(p4.x + a4.x) * w4.x + ftanh(p4.y + a4.y) * w4.y +
                    ftanh(p4.z + a4.z) * w4.z + ftanh(p4.w + a4.w) * w4.w;
        }
#pragma unroll
        for (int off = 32; off; off >>= 1) part += __shfl_down(part, off, 64);
        if (lane == 0) {
            float sc = part + bav;
            if (amask[b * 129 + 1 + m] == 0) sc = -1e9f;
            SC[b * 128 + m] = sc;
        }
    }
}

// ---------------- softmax + weighted feature sum (raw f32 enc) -> X2 att slot (hi/lo) ----------------
__global__ __launch_bounds__(256)
void k_attsum(const float* __restrict__ SC, const float* __restrict__ enc,
              u16* __restrict__ X2h, u16* __restrict__ X2l) {
    int dc = blockIdx.x, b = blockIdx.y, tid = threadIdx.x;
    __shared__ float salpha[128];
    __shared__ float sred[8];
    float sv = (tid < 128) ? SC[b * 128 + tid] : -1e30f;
    float mx = sv;
#pragma unroll
    for (int off = 32; off; off >>= 1) mx = fmaxf(mx, __shfl_down(mx, off, 64));
    if ((tid & 63) == 0) sred[tid >> 6] = mx;
    __syncthreads();
    float gmx = fmaxf(fmaxf(sred[0], sred[1]), fmaxf(sred[2], sred[3]));
    float ev = (tid < 128) ? __expf(sv - gmx) : 0.f;
    float s = ev;
#pragma unroll
    for (int off = 32; off; off >>= 1) s += __shfl_down(s, off, 64);
    if ((tid & 63) == 0) sred[4 + (tid >> 6)] = s;
    __syncthreads();
    float gsum = sred[4] + sred[5] + sred[6] + sred[7];
    if (tid < 128) salpha[tid] = ev / gsum;
    __syncthreads();
    int d = dc * 256 + tid;
    const float* base = enc + ((size_t)b * 129 + 1) * 1024 + d;
    float acc = 0.f;
#pragma unroll 8
    for (int m = 0; m < 128; ++m) acc += salpha[m] * base[(size_t)m * 1024];
    u16 hh, hl;
    split2(acc, hh, hl);
    X2h[b * 3072 + d] = hh;
    X2l[b * 3072 + d] = hl;
}

// ---------------- nce_logit[b,l,j] = ofe[b,l,:] . afe[b,j,:]  (f32) ----------------
__global__ __launch_bounds__(256)
void k_nce(const float* __restrict__ OFE, const float* __restrict__ AFE,
           const float* __restrict__ eos_w, float* __restrict__ nce) {
    int l = blockIdx.x, b = blockIdx.y;
    __shared__ float sofe[1024];
    int tid = threadIdx.x;
    {
        float4 v = *(const float4*)(OFE + ((size_t)b * 21 + l) * 1024 + tid * 4);
        *(float4*)&sofe[tid * 4] = v;
    }
    __syncthreads();
    int w = tid >> 6, lane = tid & 63;
    float* outp = nce + ((size_t)b * 21 + l) * 129;
    for (int j = w; j < 129; j += 4) {
        const float* ar = (j == 0) ? eos_w : AFE + ((size_t)b * 128 + (j - 1)) * 1024;
        float part = 0.f;
#pragma unroll
        for (int c = 0; c < 4; ++c) {
            float4 a4 = *(const float4*)(ar + c * 256 + lane * 4);
            float4 o4 = *(const float4*)&sofe[c * 256 + lane * 4];
            part += a4.x * o4.x + a4.y * o4.y + a4.z * o4.z + a4.w * o4.w;
        }
#pragma unroll
        for (int off = 32; off; off >>= 1) part += __shfl_down(part, off, 64);
        if (lane == 0) outp[j] = part;
    }
}

extern "C" void kernel_launch(void* const* d_in, const int* in_sizes, int n_in,
                              void* d_out, int out_size, void* d_ws, size_t ws_size,
                              hipStream_t stream) {
    const float* enc  = (const float*)d_in[0];
    const int*   obj  = (const int*)d_in[1];
    const int*   amask= (const int*)d_in[2];
    const float* bosw = (const float*)d_in[3];
    const float* eosw = (const float*)d_in[4];
    const float* Wp   = (const float*)d_in[5];
    const float* bp   = (const float*)d_in[6];
    const float* Wih1 = (const float*)d_in[7];
    const float* Whh1 = (const float*)d_in[8];
    const float* bih1 = (const float*)d_in[9];
    const float* bhh1 = (const float*)d_in[10];
    const float* Wih2 = (const float*)d_in[11];
    const float* Whh2 = (const float*)d_in[12];
    const float* bih2 = (const float*)d_in[13];
    const float* bhh2 = (const float*)d_in[14];
    const float* Wah  = (const float*)d_in[15];
    const float* bah  = (const float*)d_in[16];
    const float* wa   = (const float*)d_in[17];
    const float* ba   = (const float*)d_in[18];
    const float* Wae  = (const float*)d_in[19];
    const float* bae  = (const float*)d_in[20];
    const float* Woe  = (const float*)d_in[21];
    const float* boe  = (const float*)d_in[22];

    float* outputs = (float*)d_out;                    // (64,21,1024)
    float* nce     = outputs + (size_t)64 * 21 * 1024; // (64,21,129)

    char* wp = (char*)d_ws;
    auto alloc = [&](size_t bytes) -> char* { char* p = wp; wp += (bytes + 255) & ~(size_t)255; return p; };
    u16* encbf  = (u16*)alloc((size_t)64 * 129 * 1024 * 2);   // pre-scan only -> scan-state overlay
    u16* Wph    = (u16*)alloc((size_t)1024 * 1024 * 2);
    u16* Wpl    = (u16*)alloc((size_t)1024 * 1024 * 2);
    u16* Xaugh  = (u16*)alloc((size_t)1344 * 2048 * 2);       // pre-scan only -> OFE32 overlay
    u16* Xaugl  = (u16*)alloc((size_t)1344 * 2048 * 2);
    u16* W1h    = (u16*)alloc((size_t)4096 * 2048 * 2);
    u16* W1l    = (u16*)alloc((size_t)4096 * 2048 * 2);
    u16* W2h    = (u16*)alloc((size_t)4096 * 3072 * 2);
    u16* W2l    = (u16*)alloc((size_t)4096 * 3072 * 2);
    u16* Wahh   = (u16*)alloc((size_t)1024 * 1024 * 2);
    u16* Wahl   = (u16*)alloc((size_t)1024 * 1024 * 2);
    u16* Waeh   = (u16*)alloc((size_t)1024 * 1024 * 2);
    u16* Wael   = (u16*)alloc((size_t)1024 * 1024 * 2);
    u16* Woeh   = (u16*)alloc((size_t)1024 * 1024 * 2);
    u16* Woel   = (u16*)alloc((size_t)1024 * 1024 * 2);
    // region1: Wx1 hi/lo (2 * 4096*2048 * 2B = 33.5MB); after Xc GEMM reused for AFE32 (8192*1024*4B, equal)
    char* region1 = alloc((size_t)2 * 4096 * 2048 * 2);
    u16* Wx1h = (u16*)region1;
    u16* Wx1l = (u16*)region1 + (size_t)4096 * 2048;
    float* AFE32 = (float*)region1;
    float* PattF = (float*)alloc((size_t)8192 * 1024 * 4);
    float* Xcf   = (float*)alloc((size_t)1344 * 4096 * 4);
    u16* Xouth   = (u16*)alloc((size_t)1344 * 1024 * 2);
    // OFE32 overlays Xaugh (both 5,505,024 B; Xaug dead after Xc GEMM)
    float* OFE32 = (float*)Xaugh;
    // scan-state overlays encbf (encbf dead after pre-scan GEMMs)
    char* sp2 = (char*)encbf;
    auto alloc2 = [&](size_t bytes) -> char* { char* p = sp2; sp2 += (bytes + 255) & ~(size_t)255; return p; };
    float* P1  = (float*)alloc2((size_t)4 * 64 * 4096 * 4);
    float* P2  = (float*)alloc2((size_t)4 * 64 * 4096 * 4);
    float* PAH = (float*)alloc2((size_t)2 * 64 * 1024 * 4);
    u16* XHh   = (u16*)alloc2((size_t)64 * 2048 * 2);   // [h2 | h1]
    u16* XHl   = (u16*)alloc2((size_t)64 * 2048 * 2);
    u16* X2h   = (u16*)alloc2((size_t)64 * 3072 * 2);   // [att | h1 | h2]
    u16* X2l   = (u16*)alloc2((size_t)64 * 3072 * 2);
    float* c1  = (float*)alloc2((size_t)64 * 1024 * 4);
    float* c2  = (float*)alloc2((size_t)64 * 1024 * 4);
    float* SC  = (float*)alloc2((size_t)64 * 128 * 4);

    dim3 blk(256);
    // prep (encbf region live here; scan-state memsets deferred until after pre-scan GEMMs)
    k_cvt<<<2048, blk, 0, stream>>>(enc, encbf, 64 * 129 * 1024 / 4);
    k_splitp<<<1024, blk, 0, stream>>>(Wp, Wph, Wpl, 1024 * 1024 / 4);
    k_splitp<<<1024, blk, 0, stream>>>(Wah, Wahh, Wahl, 1024 * 1024 / 4);
    k_splitp<<<1024, blk, 0, stream>>>(Wae, Waeh, Wael, 1024 * 1024 / 4);
    k_splitp<<<1024, blk, 0, stream>>>(Woe, Woeh, Woel, 1024 * 1024 / 4);
    k_build_wx1<<<4096, blk, 0, stream>>>(Wih1, Wx1h, Wx1l);
    k_build_w1cat<<<4096, blk, 0, stream>>>(Wih1, Whh1, W1h, W1l);
    k_build_wcat2<<<4096, dim3(384), 0, stream>>>(Wih2, Whh2, W2h, W2l);
    k_build_xaug<<<dim3(64, 21), blk, 0, stream>>>(enc, obj, bosw, Xaugh, Xaugl);

    // p_att (f32 out, Wp split): att_feats @ Wp^T + bp
    k_gemm3<1, 2, 1, false><<<dim3(8, 64), blk, 0, stream>>>(
        encbf, nullptr, 0, Wph, Wpl, 1024, bp, nullptr, PattF, 1024, 8192, 1024);
    // Xc (A+W split, f32 out): Xaug @ Wx1^T + bih1 + bhh1   (reads region1 as Wx1)
    k_gemm3<2, 2, 0, false><<<dim3(32, 11), blk, 0, stream>>>(
        Xaugh, Xaugl, 2048, Wx1h, Wx1l, 2048, bih1, bhh1, Xcf, 4096, 1344, 2048);
    // afe (f32 out, Wae split): att_feats @ Wae^T + bae   (writes region1 as AFE32)
    k_gemm3<1, 2, 1, false><<<dim3(8, 64), blk, 0, stream>>>(
        encbf, nullptr, 0, Waeh, Wael, 1024, bae, nullptr, AFE32, 1024, 8192, 1024);

    // scan-state init (encbf now dead)
    hipMemsetAsync(XHh, 0, (size_t)64 * 2048 * 2, stream);
    hipMemsetAsync(XHl, 0, (size_t)64 * 2048 * 2, stream);
    hipMemsetAsync(X2h, 0, (size_t)64 * 3072 * 2, stream);
    hipMemsetAsync(X2l, 0, (size_t)64 * 3072 * 2, stream);
    hipMemsetAsync(c1, 0, (size_t)64 * 1024 * 4, stream);
    hipMemsetAsync(c2, 0, (size_t)64 * 1024 * 4, stream);

    for (int t = 0; t < 21; ++t) {
        // cell1 gates: [h2|h1] @ W1cat^T (4096x2048), K-split 4, 3-pass
        k_gp3<<<dim3(64, 4), blk, 0, stream>>>(XHh, XHl, 2048, W1h, W1l, 2048, 512, P1, 4096);
        // LSTM1 finish: + Xc addend (carries biases); h1 -> XH[:,1024:], X2[:,1024:2048]
        k_finish<<<256, blk, 0, stream>>>(P1, 4096, Xcf + (size_t)t * 4096, nullptr, nullptr,
                                          c1, XHh + 1024, XHl + 1024, 2048,
                                          X2h + 1024, X2l + 1024, 3072, nullptr, nullptr);
        // ah = h1_NEW @ Wah^T (K-split 2, 3-pass) — fixes the stale-h1 fusion bug
        k_gp3<<<dim3(16, 2), blk, 0, stream>>>(XHh + 1024, XHl + 1024, 2048, Wahh, Wahl, 1024, 512, PAH, 1024);
        k_score<<<dim3(4, 64), blk, 0, stream>>>(PAH, bah, wa, ba, PattF, amask, SC);
        k_attsum<<<dim3(4, 64), blk, 0, stream>>>(SC, enc, X2h, X2l);
        // cell2 gates: [att|h1|h2] @ Wcat2^T, K-split 4, 3-pass
        k_gp3<<<dim3(64, 4), blk, 0, stream>>>(X2h, X2l, 3072, W2h, W2l, 3072, 768, P2, 4096);
        // LSTM2 finish: h2 -> XH[:,0:], X2[:,2048:], outputs, Xout(hi)
        k_finish<<<256, blk, 0, stream>>>(P2, 4096, nullptr, bih2, bhh2,
                                          c2, XHh, XHl, 2048,
                                          X2h + 2048, X2l + 2048, 3072,
                                          outputs + (size_t)t * 1024, Xouth + (size_t)t * 1024);
    }

    // ofe = outputs @ Woe^T + boe (f32 out, Woe split; overlays dead Xaug region)
    k_gemm3<1, 2, 0, false><<<dim3(8, 11), blk, 0, stream>>>(
        Xouth, nullptr, 1024, Woeh, Woel, 1024, boe, nullptr, OFE32, 1024, 1344, 1024);
    k_nce<<<dim3(21, 64), blk, 0, stream>>>(OFE32, AFE32, eosw, nce);
}